// Round 8
// baseline (308.716 us; speedup 1.0000x reference)
//
#include <hip/hip_runtime.h>
#include <hip/hip_bf16.h>
#include <math.h>

#define B_ROWS 32768

typedef __attribute__((ext_vector_type(8)))  short        s8v;
typedef __attribute__((ext_vector_type(4)))  float        f4v;
typedef __attribute__((ext_vector_type(2)))  unsigned int u2v;
typedef __attribute__((ext_vector_type(4)))  unsigned int u4v;

__device__ __forceinline__ short f2bf(float f){            // f32 -> bf16 RNE (cvtw helper)
  unsigned u = __builtin_bit_cast(unsigned, f);
  u = (u + 0x7fffu + ((u >> 16) & 1u)) >> 16;
  return (short)u;
}
// packed pair convert (RNE, low = a, high = b) — compiler fuses the two casts
// into v_cvt_pk_bf16_f32 (learn_hip m240); NO inline asm (rounds 2/7 NaN'd with it)
__device__ __forceinline__ unsigned cpk(float a, float b){
  __hip_bfloat16_raw lo = (__hip_bfloat16_raw)__float2bfloat16(a);
  __hip_bfloat16_raw hi = (__hip_bfloat16_raw)__float2bfloat16(b);
  return (unsigned)lo.x | ((unsigned)hi.x << 16);
}
__device__ __forceinline__ float bf_lo(unsigned u){ return __builtin_bit_cast(float, u << 16); }
__device__ __forceinline__ float bf_hi(unsigned u){ return __builtin_bit_cast(float, u & 0xffff0000u); }

#define MFMA16(A,B,C) __builtin_amdgcn_mfma_f32_16x16x32_bf16((A),(B),(C),0,0,0)

// ---------------- LDS layout (bytes) ----------------
#define OXFT 0        // f32 [64][132] x-state transposed [dim][batch]
#define XFT_S 132
#define OHB  33792    // bf16 [128][136] hidden chunk (per-wave disjoint regions)
#define HB_S 136
#define OW1  68608    // 2 x bf16 [128][168] W1 chunk double buffer
#define W1BUF 43008
#define W1_S 168
#define OLJ  154624   // f32[128]
#define OPERM 155136  // int[64]
#define OELS 155392   // f32[64]
#define OBIV 155648   // f32[64]
#define OSLS 155904   // f32 scalar
#define SM_SZ 155920

// reduce slots: bf16 [128][68] each (17408 B). Slots 0,1 alias dead W1 buf1;
// slots 2,3 alias dead HB. Written after post-chunk3 barrier, consumed in
// coupling before next MLP touches buf1/HB.
#define SL_S 68
#define SLOT_B 17408
#define OSL0 (OW1 + W1BUF)

// ws (bf16 weights) element offsets
#define O_S1W1 0
#define O_S1W2 983040
#define O_S2W1 1376256
#define O_S2W2 2359296
#define W_TOTAL 2752512

__global__ void cvtw(const float* __restrict__ s1w1, const float* __restrict__ s1w2,
                     const float* __restrict__ s2w1, const float* __restrict__ s2w2,
                     unsigned short* __restrict__ dst)
{
  long t = (long)blockIdx.x * blockDim.x + threadIdx.x;
  if (t >= W_TOTAL) return;
  float v;
  if      (t < O_S1W2) v = s1w1[t];
  else if (t < O_S2W1) v = s1w2[t - O_S1W2];
  else if (t < O_S2W2) v = s2w1[t - O_S2W1];
  else                 v = s2w2[t - O_S2W2];
  dst[t] = (unsigned short)f2bf(v);
}

template<int USEBF>
__device__ __forceinline__ s8v ldw(const unsigned short* wb, const float* wf, int off){
  if (USEBF){
    return *(const s8v*)(wb + off);
  } else {
    f4v a = *(const f4v*)(wf + off);
    f4v b = *(const f4v*)(wf + off + 4);
    u4v u = {cpk(a[0],a[1]), cpk(a[2],a[3]), cpk(b[0],b[1]), cpk(b[2],b[3])};
    return __builtin_bit_cast(s8v, u);
  }
}

struct MP { const unsigned short* w1b; const float* w1f;
            const unsigned short* w2b; const float* w2f;
            const float* b1; const float* b2; };

__device__ __forceinline__ MP getmp(int m, const unsigned short* wbf,
    const float* s1W1f, const float* s1W2f, const float* s2W1f, const float* s2W2f,
    const float* s1b1, const float* s1b2, const float* s2b1, const float* s2b2)
{
  int blk = m >> 1;
  MP r;
  if (m & 1){
    r.w1b = wbf + O_S1W1 + (size_t)blk*81920; r.w1f = s1W1f + (size_t)blk*81920;
    r.w2b = wbf + O_S1W2 + (size_t)blk*32768; r.w2f = s1W2f + (size_t)blk*32768;
    r.b1 = s1b1 + blk*512; r.b2 = s1b2 + blk*64;
  } else {
    r.w1b = wbf + O_S2W1 + (size_t)blk*81920; r.w1f = s2W1f + (size_t)blk*81920;
    r.w2b = wbf + O_S2W2 + (size_t)blk*32768; r.w2f = s2W2f + (size_t)blk*32768;
    r.b1 = s2b1 + blk*512; r.b2 = s2b2 + blk*64;
  }
  return r;
}

// issue coalesced global loads of one 128-hidden W1 chunk into registers
template<int USEBF>
__device__ __forceinline__ void issue_w1(const MP& p, int cchunk, int tid,
                                         u4v wt[5], f4v wtf[10])
{
  if (USEBF){
    const unsigned short* s = p.w1b + cchunk*20480;
    #pragma unroll
    for (int k = 0; k < 5; ++k) wt[k] = *(const u4v*)(s + (size_t)(k*512+tid)*8);
  } else {
    const float* s = p.w1f + cchunk*20480;
    #pragma unroll
    for (int k = 0; k < 10; ++k) wtf[k] = *(const f4v*)(s + (size_t)(k*512+tid)*4);
  }
}

// write staged W1 registers into padded LDS buffer (row/col precomputed)
template<int USEBF>
__device__ __forceinline__ void write_w1(char* sm, int buf,
                                         const u4v wt[5], const f4v wtf[10],
                                         const int* wr, const int* wc)
{
  short* W1n = (short*)(sm + OW1 + buf*W1BUF);
  if (USEBF){
    #pragma unroll
    for (int k = 0; k < 5; ++k)
      *(u4v*)(W1n + wr[k]*W1_S + wc[k]*8) = wt[k];
  } else {
    #pragma unroll
    for (int k = 0; k < 10; ++k){
      f4v v = wtf[k];
      *(u2v*)(W1n + wr[k]*W1_S + wc[k]*4) = (u2v){cpk(v[0],v[1]), cpk(v[2],v[3])};
    }
  }
}

// W2 A-frags: all 4 out-tiles, k-slice = this wave's 32 hidden rows of chunk c
template<int USEBF>
__device__ __forceinline__ void load_w2(const MP& p, int c, int hw, int l15, int lq, s8v w2o[4]){
  #pragma unroll
  for (int ot = 0; ot < 4; ++ot)
    w2o[ot] = ldw<USEBF>(p.w2b, p.w2f, (ot*16 + l15)*512 + c*128 + hw*32 + lq*8);
}

// ---- one MLP: h^T = relu(W1 x^T + b1); r^T = W2 h^T + b2; coupling ----
template<int USEBF>
__device__ __forceinline__ void mlp_body(char* sm, int tid, int m,
    const MP& cur, const MP& nxt, const s8v hfr[4][4], s8v w2cur[4],
    f4v b1cur[2], f4v b2cur[4], const int* wr, const int* wc)
{
  const int lane = tid & 63, wave = tid >> 6;
  const int hw = wave >> 1, ng = wave & 1;
  const int l15 = lane & 15, lq = lane >> 4;
  const int bp = m & 1;
  float* XFT = (float*)(sm + OXFT);
  short* HB  = (short*)(sm + OHB);
  float* LOGJ= (float*)(sm + OLJ);

  // x-part B-frags from XFT (dims xbase..+31), packed converts
  const int xbase = bp ? 0 : 32;
  s8v xk[4];
  #pragma unroll
  for (int nt = 0; nt < 4; ++nt){
    int b = ng*64 + nt*16 + l15;
    const float* xp = XFT + (xbase + lq*8)*XFT_S + b;
    u4v u;
    #pragma unroll
    for (int p = 0; p < 4; ++p)
      u[p] = cpk(xp[(2*p)*XFT_S], xp[(2*p+1)*XFT_S]);
    xk[nt] = __builtin_bit_cast(s8v, u);
  }

  // GEMM2 k-partial accumulators; b2 carried by hw==0 waves only
  f4v racc[4][4];
  #pragma unroll
  for (int ot = 0; ot < 4; ++ot){
    f4v bv = (f4v){0.f,0.f,0.f,0.f};
    if (hw == 0) bv = b2cur[ot];
    #pragma unroll
    for (int nt = 0; nt < 4; ++nt) racc[ot][nt] = bv;
  }

  #pragma unroll
  for (int c = 0; c < 4; ++c){
    // prefetch next W1 chunk + next b1 (global -> regs)
    u4v wt[5]; f4v wtf[10];
    const MP& pn = (c < 3) ? cur : nxt;
    const int cn = (c < 3) ? c + 1 : 0;
    issue_w1<USEBF>(pn, cn, tid, wt, wtf);
    f4v b1n0 = *(const f4v*)(pn.b1 + cn*128 + hw*32 + lq*4);
    f4v b1n1 = *(const f4v*)(pn.b1 + cn*128 + hw*32 + 16 + lq*4);
    if (c == 3 && hw == 0){
      #pragma unroll
      for (int ot = 0; ot < 4; ++ot)
        b2cur[ot] = *(const f4v*)(nxt.b2 + ot*16 + lq*4);
    }

    // ---- GEMM1 chunk c: hidden rows c*128 + hw*32 + {0,16}
    const short* W1c = (const short*)(sm + OW1 + (c&1)*W1BUF);
    f4v acc[2][4];
    #pragma unroll
    for (int mt = 0; mt < 2; ++mt){
      f4v bv = b1cur[mt];
      #pragma unroll
      for (int nt = 0; nt < 4; ++nt) acc[mt][nt] = bv;
    }
    #pragma unroll
    for (int kk = 0; kk < 5; ++kk){
      s8v a0 = *(const s8v*)(W1c + (hw*32 +  0 + l15)*W1_S + kk*32 + lq*8);
      s8v a1 = *(const s8v*)(W1c + (hw*32 + 16 + l15)*W1_S + kk*32 + lq*8);
      #pragma unroll
      for (int nt = 0; nt < 4; ++nt){
        s8v bb = (kk == 0) ? xk[nt] : hfr[nt][kk-1];
        acc[0][nt] = MFMA16(a0, bb, acc[0][nt]);
        acc[1][nt] = MFMA16(a1, bb, acc[1][nt]);
      }
    }
    // relu + packed convert -> own HB region
    #pragma unroll
    for (int mt = 0; mt < 2; ++mt)
      #pragma unroll
      for (int nt = 0; nt < 4; ++nt){
        float h0 = fmaxf(acc[mt][nt][0],0.f), h1 = fmaxf(acc[mt][nt][1],0.f);
        float h2 = fmaxf(acc[mt][nt][2],0.f), h3 = fmaxf(acc[mt][nt][3],0.f);
        *(u2v*)(HB + (ng*64 + nt*16 + l15)*HB_S + hw*32 + mt*16 + lq*4) = (u2v){cpk(h0,h1), cpk(h2,h3)};
      }
    // ---- GEMM2 k-slice: read back OWN rows (in-wave, no barrier)
    #pragma unroll
    for (int nt = 0; nt < 4; ++nt){
      s8v bb = *(const s8v*)(HB + (ng*64 + nt*16 + l15)*HB_S + hw*32 + lq*8);
      #pragma unroll
      for (int ot = 0; ot < 4; ++ot)
        racc[ot][nt] = MFMA16(w2cur[ot], bb, racc[ot][nt]);
    }
    // commit staged W1, rotate prefetched operands
    write_w1<USEBF>(sm, cn & 1, wt, wtf, wr, wc);
    b1cur[0] = b1n0; b1cur[1] = b1n1;
    load_w2<USEBF>(pn, cn, hw, l15, lq, w2cur);
    __syncthreads();
  }

  // ---- reduce k-partials: every wave writes its bf16 slot (aliases dead buf1/HB)
  {
    short* SL = (hw < 2) ? (short*)(sm + OSL0 + hw*SLOT_B)
                         : (short*)(sm + OHB + (hw-2)*SLOT_B);
    #pragma unroll
    for (int ot = 0; ot < 4; ++ot)
      #pragma unroll
      for (int nt = 0; nt < 4; ++nt)
        *(u2v*)(SL + (ng*64 + nt*16 + l15)*SL_S + ot*16 + lq*4) =
          (u2v){cpk(racc[ot][nt][0], racc[ot][nt][1]), cpk(racc[ot][nt][2], racc[ot][nt][3])};
  }
  __syncthreads();

  // ---- coupling: sum 4 slots, le = 0.636*atan(rL); y = exp(le)*x_half + rR
  {
    int b = tid & 127, og = tid >> 7;
    float le[8] = {0,0,0,0,0,0,0,0}, ra[8] = {0,0,0,0,0,0,0,0};
    #pragma unroll
    for (int mslot = 0; mslot < 4; ++mslot){
      const short* SL = (mslot < 2) ? (const short*)(sm + OSL0 + mslot*SLOT_B)
                                    : (const short*)(sm + OHB + (mslot-2)*SLOT_B);
      u2v L0 = *(const u2v*)(SL + b*SL_S + og*8);
      u2v L1 = *(const u2v*)(SL + b*SL_S + og*8 + 4);
      u2v R0 = *(const u2v*)(SL + b*SL_S + 32 + og*8);
      u2v R1 = *(const u2v*)(SL + b*SL_S + 32 + og*8 + 4);
      le[0]+=bf_lo(L0[0]); le[1]+=bf_hi(L0[0]); le[2]+=bf_lo(L0[1]); le[3]+=bf_hi(L0[1]);
      le[4]+=bf_lo(L1[0]); le[5]+=bf_hi(L1[0]); le[6]+=bf_lo(L1[1]); le[7]+=bf_hi(L1[1]);
      ra[0]+=bf_lo(R0[0]); ra[1]+=bf_hi(R0[0]); ra[2]+=bf_lo(R0[1]); ra[3]+=bf_hi(R0[1]);
      ra[4]+=bf_lo(R1[0]); ra[5]+=bf_hi(R1[0]); ra[6]+=bf_lo(R1[1]); ra[7]+=bf_hi(R1[1]);
    }
    float part = 0.f;
    #pragma unroll
    for (int j = 0; j < 8; ++j){
      float l = 0.636f * atanf(le[j]);
      int d = bp*32 + og*8 + j;
      float y = __expf(l) * XFT[d*XFT_S + b] + ra[j];
      XFT[d*XFT_S + b] = y;
      part += l;
    }
    atomicAdd(&LOGJ[b], part);
  }
  __syncthreads();
}

template<int USEBF>
__global__ __launch_bounds__(512, 1) void cinn_t(
    const float* __restrict__ q, const float* __restrict__ Hg,
    const int* __restrict__ perms,
    const float* __restrict__ ls_g, const float* __restrict__ bi_g,
    const float* __restrict__ s1b1, const float* __restrict__ s1b2,
    const float* __restrict__ s2b1, const float* __restrict__ s2b2,
    const unsigned short* __restrict__ wbf,
    const float* __restrict__ s1W1f, const float* __restrict__ s1W2f,
    const float* __restrict__ s2W1f, const float* __restrict__ s2W2f,
    float* __restrict__ outz, float* __restrict__ outlj)
{
  __shared__ __align__(16) char sm[SM_SZ];
  const int tid = threadIdx.x;
  const int rowbase = blockIdx.x * 128;
  const int lane = tid & 63, wave = tid >> 6;
  const int hw = wave >> 1, ng = wave & 1;
  const int l15 = lane & 15, lq = lane >> 4;

  float* XFT = (float*)(sm + OXFT);
  float* LOGJ = (float*)(sm + OLJ);
  int*   PERM = (int*)(sm + OPERM);
  float* ELS  = (float*)(sm + OELS);
  float* BIV  = (float*)(sm + OBIV);
  float* SLSp = (float*)(sm + OSLS);

  // precompute W1 staging row/col (runtime div done once)
  int wr[10], wc[10];
  if (USEBF){
    #pragma unroll
    for (int k = 0; k < 5; ++k){ int i = k*512 + tid; wr[k] = i/20; wc[k] = i - wr[k]*20; }
  } else {
    #pragma unroll
    for (int k = 0; k < 10; ++k){ int i = k*512 + tid; wr[k] = i/40; wc[k] = i - wr[k]*40; }
  }

  // init XFT from q (coalesced read, strided LDS write, once)
  {
    int b = tid >> 2, j = tid & 3;
    const float* src = q + (size_t)(rowbase + b)*64 + j*16;
    #pragma unroll
    for (int i = 0; i < 4; ++i){
      f4v v = *(const f4v*)(src + 4*i);
      #pragma unroll
      for (int jj = 0; jj < 4; ++jj)
        XFT[(j*16 + 4*i + jj)*XFT_S + b] = v[jj];
    }
  }
  if (tid < 128) LOGJ[tid] = 0.f;
  if (tid == 0)  *SLSp = 0.f;
  __syncthreads();
  if (tid < 64){
    float p = 0.f;
    #pragma unroll
    for (int k = 0; k < 12; ++k) p += ls_g[k*64 + tid];
    atomicAdd(SLSp, p);
  }

  // H-part B-fragments: loaded ONCE, register-resident
  s8v hfr[4][4];
  #pragma unroll
  for (int nt = 0; nt < 4; ++nt){
    int b = rowbase + ng*64 + nt*16 + l15;
    #pragma unroll
    for (int kkh = 0; kkh < 4; ++kkh){
      const float* hp = Hg + (size_t)b*128 + kkh*32 + lq*8;
      f4v a = *(const f4v*)hp;
      f4v c = *(const f4v*)(hp + 4);
      u4v u = {cpk(a[0],a[1]), cpk(a[2],a[3]), cpk(c[0],c[1]), cpk(c[2],c[3])};
      hfr[nt][kkh] = __builtin_bit_cast(s8v, u);
    }
  }

  // prologue: stage MLP0 chunk0 weights + bias regs
  s8v w2cur[4];
  f4v b1cur[2], b2cur[4];
  {
    MP p0 = getmp(0, wbf, s1W1f, s1W2f, s2W1f, s2W2f, s1b1, s1b2, s2b1, s2b2);
    u4v wt[5]; f4v wtf[10];
    issue_w1<USEBF>(p0, 0, tid, wt, wtf);
    write_w1<USEBF>(sm, 0, wt, wtf, wr, wc);
    b1cur[0] = *(const f4v*)(p0.b1 + hw*32 + lq*4);
    b1cur[1] = *(const f4v*)(p0.b1 + hw*32 + 16 + lq*4);
    if (hw == 0){
      #pragma unroll
      for (int ot = 0; ot < 4; ++ot)
        b2cur[ot] = *(const f4v*)(p0.b2 + ot*16 + lq*4);
    }
    load_w2<USEBF>(p0, 0, hw, l15, lq, w2cur);
  }

  for (int m = 0; m < 24; ++m){
    if (!(m & 1)){
      int blk = m >> 1;
      if (tid < 64){
        PERM[tid] = perms[blk*64 + tid];
        ELS[tid]  = __expf(ls_g[blk*64 + tid]);
        BIV[tid]  = bi_g[blk*64 + tid];
      }
      __syncthreads();
      // permute + affine on XFT (read-all / barrier / write-all)
      {
        int d = lane, bg = wave;
        int pd = PERM[d];
        f4v v[4];
        #pragma unroll
        for (int i = 0; i < 4; ++i)
          v[i] = *(const f4v*)(XFT + pd*XFT_S + bg*16 + 4*i);
        __syncthreads();
        float e = ELS[d], bi = BIV[d];
        #pragma unroll
        for (int i = 0; i < 4; ++i){
          #pragma unroll
          for (int jj = 0; jj < 4; ++jj) v[i][jj] = fmaf(v[i][jj], e, bi);
          *(f4v*)(XFT + d*XFT_S + bg*16 + 4*i) = v[i];
        }
      }
      __syncthreads();
    }
    MP cur = getmp(m, wbf, s1W1f, s1W2f, s2W1f, s2W2f, s1b1, s1b2, s2b1, s2b2);
    MP nxt = getmp(m < 23 ? m + 1 : 23, wbf, s1W1f, s1W2f, s2W1f, s2W2f, s1b1, s1b2, s2b1, s2b2);
    mlp_body<USEBF>(sm, tid, m, cur, nxt, hfr, w2cur, b1cur, b2cur, wr, wc);
  }

  // output: transpose back, coalesced global writes
  {
    int b = tid >> 2, j = tid & 3;
    float* dst = outz + (size_t)(rowbase + b)*64 + j*16;
    #pragma unroll
    for (int i = 0; i < 4; ++i){
      f4v w;
      #pragma unroll
      for (int jj = 0; jj < 4; ++jj)
        w[jj] = XFT[(j*16 + 4*i + jj)*XFT_S + b];
      *(f4v*)(dst + 4*i) = w;
    }
  }
  if (tid < 128) outlj[rowbase + tid] = LOGJ[tid] + *SLSp;
}

extern "C" void kernel_launch(void* const* d_in, const int* in_sizes, int n_in,
                              void* d_out, int out_size, void* d_ws, size_t ws_size,
                              hipStream_t stream)
{
  const float* q    = (const float*)d_in[0];
  const float* Hg   = (const float*)d_in[1];
  const int*   perms= (const int*)  d_in[2];
  const float* ls   = (const float*)d_in[3];
  const float* bi   = (const float*)d_in[4];
  const float* s1W1 = (const float*)d_in[5];
  const float* s1b1 = (const float*)d_in[6];
  const float* s1W2 = (const float*)d_in[7];
  const float* s1b2 = (const float*)d_in[8];
  const float* s2W1 = (const float*)d_in[9];
  const float* s2b1 = (const float*)d_in[10];
  const float* s2W2 = (const float*)d_in[11];
  const float* s2b2 = (const float*)d_in[12];
  float* outz  = (float*)d_out;
  float* outlj = outz + (size_t)B_ROWS * 64;

  int usebf = (ws_size >= (size_t)W_TOTAL * 2) ? 1 : 0;
  unsigned short* wbf = (unsigned short*)d_ws;
  if (usebf){
    cvtw<<<2688, 1024, 0, stream>>>(s1W1, s1W2, s2W1, s2W2, wbf);
    cinn_t<1><<<256, 512, 0, stream>>>(q, Hg, perms, ls, bi,
                                       s1b1, s1b2, s2b1, s2b2,
                                       wbf, s1W1, s1W2, s2W1, s2W2,
                                       outz, outlj);
  } else {
    cinn_t<0><<<256, 512, 0, stream>>>(q, Hg, perms, ls, bi,
                                       s1b1, s1b2, s2b1, s2b2,
                                       wbf, s1W1, s1W2, s2W1, s2W2,
                                       outz, outlj);
  }
}